// Round 2
// baseline (1608.160 us; speedup 1.0000x reference)
//
#include <hip/hip_runtime.h>

#define BB 4
#define TT 2048
#define HH 16
#define ROWS (BB*TT)

typedef unsigned short u16;
typedef __bf16 bf16x8 __attribute__((ext_vector_type(8)));
typedef float f32x4 __attribute__((ext_vector_type(4)));
typedef u16 u16x8 __attribute__((ext_vector_type(8)));
typedef u16 u16x4 __attribute__((ext_vector_type(4)));

__device__ __forceinline__ u16 f2bf(float f) {
  unsigned u = __float_as_uint(f);
  u += 0x7fffu + ((u >> 16) & 1u);
  return (u16)(u >> 16);
}
__device__ __forceinline__ float bf2f(u16 h) {
  return __uint_as_float(((unsigned)h) << 16);
}

__device__ __forceinline__ void gload_lds16(const u16* g, u16* l) {
  __builtin_amdgcn_global_load_lds((const __attribute__((address_space(1))) void*)g,
                                   (__attribute__((address_space(3))) void*)l, 16, 0, 0);
}

// ---------------- cast fp32 -> bf16 (optionally scaled) ----------------
__global__ __launch_bounds__(256) void cast_bf16(const float* __restrict__ in,
                                                 u16* __restrict__ out,
                                                 long n, float scale) {
  long i = ((long)blockIdx.x * 256 + threadIdx.x) * 4;
  long stride = (long)gridDim.x * 1024;
  for (; i < n; i += stride) {
    float4 v = *(const float4*)(in + i);
    u16x4 o = { f2bf(v.x*scale), f2bf(v.y*scale), f2bf(v.z*scale), f2bf(v.w*scale) };
    *(u16x4*)(out + i) = o;
  }
}

// cast with zero-padding past n_in (replaces memset for padded weight)
__global__ __launch_bounds__(256) void cast_pad(const float* __restrict__ in,
                                                u16* __restrict__ out,
                                                long n_in, long n_total) {
  long i = ((long)blockIdx.x * 256 + threadIdx.x) * 4;
  long stride = (long)gridDim.x * 1024;
  for (; i < n_total; i += stride) {
    u16x4 o;
    if (i + 3 < n_in) {
      float4 v = *(const float4*)(in + i);
      o = (u16x4){ f2bf(v.x), f2bf(v.y), f2bf(v.z), f2bf(v.w) };
    } else {
#pragma unroll
      for (int e = 0; e < 4; ++e) o[e] = (i + e < n_in) ? f2bf(in[i+e]) : (u16)0;
    }
    *(u16x4*)(out + i) = o;
  }
}

// ---------------- GEMM: C[M,N] = A[M,K] (bf16) * B[N,K]^T (bf16) ----------------
// m97 structure: 128x128 tile, BK=64, 4 waves, global_load_lds width 16.
template<int OUT_BF16>
__global__ __launch_bounds__(256) void gemm_bt(const u16* __restrict__ A,
                                               const u16* __restrict__ Bm,
                                               void* __restrict__ Cv,
                                               int M, int N, int K) {
  __shared__ __align__(16) u16 As[128*64];
  __shared__ __align__(16) u16 Bs[128*64];
  const int tid = threadIdx.x;
  const int lane = tid & 63;
  const int wid = tid >> 6;
  const int m0 = blockIdx.y << 7;
  const int n0 = blockIdx.x << 7;
  const int wm = (wid >> 1) << 6;
  const int wn = (wid & 1) << 6;
  const int lrow = lane & 15;
  const int lk = (lane >> 4) << 3;

  f32x4 acc[4][4] = {};

  for (int k0 = 0; k0 < K; k0 += 64) {
#pragma unroll
    for (int c = 0; c < 4; ++c) {
      int idx = c*256 + tid;
      int r = idx >> 3;
      int col = (idx & 7) << 3;
      const u16* ga = A  + (long)(m0 + r) * K + k0 + col;
      const u16* gb = Bm + (long)(n0 + r) * K + k0 + col;
      u16* la = As + (c*256 + (wid << 6)) * 8;
      u16* lb = Bs + (c*256 + (wid << 6)) * 8;
      gload_lds16(ga, la);
      gload_lds16(gb, lb);
    }
    __syncthreads();
    bf16x8 af[4][2], bfr[4][2];
#pragma unroll
    for (int m = 0; m < 4; ++m) {
      af[m][0] = *(const bf16x8*)(As + (wm + m*16 + lrow)*64 + lk);
      af[m][1] = *(const bf16x8*)(As + (wm + m*16 + lrow)*64 + 32 + lk);
    }
#pragma unroll
    for (int n = 0; n < 4; ++n) {
      bfr[n][0] = *(const bf16x8*)(Bs + (wn + n*16 + lrow)*64 + lk);
      bfr[n][1] = *(const bf16x8*)(Bs + (wn + n*16 + lrow)*64 + 32 + lk);
    }
#pragma unroll
    for (int ks = 0; ks < 2; ++ks)
#pragma unroll
      for (int m = 0; m < 4; ++m)
#pragma unroll
        for (int n = 0; n < 4; ++n)
          acc[m][n] = __builtin_amdgcn_mfma_f32_16x16x32_bf16(af[m][ks], bfr[n][ks], acc[m][n], 0, 0, 0);
    __syncthreads();
  }

  const int orow = (lane >> 4) << 2;
  const int ocol = lane & 15;
#pragma unroll
  for (int m = 0; m < 4; ++m)
#pragma unroll
    for (int n = 0; n < 4; ++n) {
      long rbase = (long)(m0 + wm + m*16 + orow);
      int col = n0 + wn + n*16 + ocol;
#pragma unroll
      for (int r = 0; r < 4; ++r) {
        if (OUT_BF16) ((u16*)Cv)[(rbase + r) * (long)N + col] = f2bf(acc[m][n][r]);
        else          ((float*)Cv)[(rbase + r) * (long)N + col] = acc[m][n][r];
      }
    }
}

// ---------------- RMSNorm (bf16 in -> bf16 out, fp32 accumulate) ----------------
__global__ __launch_bounds__(256) void rmsnorm_bf(const u16* __restrict__ in, int istride,
                                                  const float* __restrict__ w,
                                                  u16* __restrict__ out, int ostride,
                                                  int N, float invn) {
  const long row = blockIdx.x;
  const u16* x = in + row * istride;
  u16* y = out + row * ostride;
  float ss = 0.f;
  for (int i = threadIdx.x * 8; i < N; i += 2048) {
    u16x8 v = *(const u16x8*)(x + i);
#pragma unroll
    for (int e = 0; e < 8; ++e) { float f = bf2f(v[e]); ss += f*f; }
  }
#pragma unroll
  for (int off = 32; off > 0; off >>= 1) ss += __shfl_down(ss, off);
  __shared__ float red[4];
  if ((threadIdx.x & 63) == 0) red[threadIdx.x >> 6] = ss;
  __syncthreads();
  float rms = rsqrtf((red[0]+red[1]+red[2]+red[3]) * invn + 1e-6f);
  for (int i = threadIdx.x * 8; i < N; i += 2048) {
    u16x8 v = *(const u16x8*)(x + i);
    u16x8 o;
#pragma unroll
    for (int e = 0; e < 8; ++e) o[e] = f2bf(bf2f(v[e]) * rms * w[i+e]);
    *(u16x8*)(y + i) = o;
  }
}

// ---------------- RoPE: q_rope in-place (+scale), k_rope -> Kr ----------------
__global__ __launch_bounds__(256) void rope_qk(u16* __restrict__ qr,          // [ROWS,1024]
                                               const u16* __restrict__ kvb0,  // [ROWS,640] bf16
                                               u16* __restrict__ Kr,          // [ROWS,64]
                                               const float* __restrict__ cosb,
                                               const float* __restrict__ sinb) {
  const int row = blockIdx.x;
  const int t = row & (TT-1);
  const float sc = 0.07216878364870322f;   // 1/sqrt(192)
  for (int p = threadIdx.x; p < 512; p += 256) {
    int h = p >> 5, i = p & 31;
    long base = (long)row*1024 + h*64 + 2*i;
    float x0 = bf2f(qr[base]), x1 = bf2f(qr[base+1]);
    float c = cosb[t*32 + i], s = sinb[t*32 + i];
    qr[base]   = f2bf((x0*c - x1*s)*sc);
    qr[base+1] = f2bf((x0*s + x1*c)*sc);
  }
  if (threadIdx.x < 32) {
    int i = threadIdx.x;
    float x0 = bf2f(kvb0[(long)row*640 + 512 + 2*i]);
    float x1 = bf2f(kvb0[(long)row*640 + 512 + 2*i + 1]);
    float c = cosb[t*32 + i], s = sinb[t*32 + i];
    Kr[row*64 + 2*i]   = f2bf(x0*c - x1*s);
    Kr[row*64 + 2*i+1] = f2bf(x0*s + x1*c);
  }
}

// ---------------- V transpose: kv[...,h*256+128+d] -> Vt[b,h,d,t] ----------------
__global__ __launch_bounds__(256) void transpose_v(const u16* __restrict__ kvb,
                                                   u16* __restrict__ Vt) {
  __shared__ u16 tile[64][136];
  const int bh = blockIdx.y;
  const int t0 = blockIdx.x << 6;
  const int tid = threadIdx.x;
  const long rowbase = (long)(bh >> 4) * TT + t0;
#pragma unroll
  for (int it = 0; it < 4; ++it) {
    int r = it*16 + (tid >> 4);
    int c = (tid & 15) << 3;
    u16x8 v = *(const u16x8*)(kvb + (rowbase + r) * 4096 + (bh & 15) * 256 + 128 + c);
#pragma unroll
    for (int e = 0; e < 8; ++e) tile[r][c+e] = v[e];
  }
  __syncthreads();
#pragma unroll
  for (int it = 0; it < 4; ++it) {
    int d = it*32 + (tid >> 3);
    int tc = (tid & 7) << 3;
    u16x8 o;
#pragma unroll
    for (int e = 0; e < 8; ++e) o[e] = tile[tc+e][d];
    *(u16x8*)(Vt + ((long)bh * 128 + d) * TT + t0 + tc) = o;
  }
}

// ---------------- Flash attention (causal), 4 waves x 16 q-rows, KV tile 32 ----------------
__global__ __launch_bounds__(256) void flash_attn(const u16* __restrict__ qn,  // [ROWS,2048] pre-scaled
                                                  const u16* __restrict__ qr,  // [ROWS,1024] roped+scaled
                                                  const u16* __restrict__ kvb, // [ROWS,4096]
                                                  const u16* __restrict__ kr,  // [ROWS,64]
                                                  const u16* __restrict__ Vt,  // [B*H,128,T]
                                                  u16* __restrict__ O) {       // [ROWS,2048]
  __shared__ __align__(16) u16 Pl[4][16*32];
  const int bh = blockIdx.y;
  const int b = bh >> 4, h = bh & 15;
  const int wid = threadIdx.x >> 6, lane = threadIdx.x & 63;
  const int q0 = (blockIdx.x << 6) + (wid << 4);
  const int lrow = lane & 15, lk = (lane >> 4) << 3;

  const long browq = (long)b * TT + q0;
  bf16x8 qf[6];
#pragma unroll
  for (int ks = 0; ks < 4; ++ks)
    qf[ks] = *(const bf16x8*)(qn + (browq + lrow) * 2048 + h*128 + ks*32 + lk);
#pragma unroll
  for (int ks = 4; ks < 6; ++ks)
    qf[ks] = *(const bf16x8*)(qr + (browq + lrow) * 1024 + h*64 + (ks-4)*32 + lk);

  f32x4 oacc[8] = {};
  float mrun[4], lrun[4];
#pragma unroll
  for (int r = 0; r < 4; ++r) { mrun[r] = -1e30f; lrun[r] = 0.f; }

  u16* Pw = &Pl[wid][0];
  const long browk = (long)b * TT;
  const u16* vbase = Vt + (long)bh * 128 * TT;

  const int smax = q0 + 15;
  for (int s0 = 0; s0 <= smax; s0 += 32) {
    f32x4 sacc[2] = {};
#pragma unroll
    for (int nt = 0; nt < 2; ++nt) {
      long krow = browk + s0 + nt*16 + lrow;
#pragma unroll
      for (int ks = 0; ks < 4; ++ks) {
        bf16x8 kf = *(const bf16x8*)(kvb + krow*4096 + h*256 + ks*32 + lk);
        sacc[nt] = __builtin_amdgcn_mfma_f32_16x16x32_bf16(qf[ks], kf, sacc[nt], 0, 0, 0);
      }
#pragma unroll
      for (int ks = 4; ks < 6; ++ks) {
        bf16x8 kf = *(const bf16x8*)(kr + krow*64 + (ks-4)*32 + lk);
        sacc[nt] = __builtin_amdgcn_mfma_f32_16x16x32_bf16(qf[ks], kf, sacc[nt], 0, 0, 0);
      }
    }
    const int qrow_base = q0 + ((lane >> 4) << 2);
    float tm[4];
#pragma unroll
    for (int r = 0; r < 4; ++r) {
      int qrow = qrow_base + r;
      if (s0 + (lane & 15) > qrow)      sacc[0][r] = -1e30f;
      if (s0 + 16 + (lane & 15) > qrow) sacc[1][r] = -1e30f;
      tm[r] = fmaxf(sacc[0][r], sacc[1][r]);
    }
#pragma unroll
    for (int x = 1; x < 16; x <<= 1)
#pragma unroll
      for (int r = 0; r < 4; ++r) tm[r] = fmaxf(tm[r], __shfl_xor(tm[r], x));
    float alpha[4], psum[4];
#pragma unroll
    for (int r = 0; r < 4; ++r) {
      float mn = fmaxf(mrun[r], tm[r]);
      alpha[r] = __expf(mrun[r] - mn);
      mrun[r] = mn;
      float p0 = __expf(sacc[0][r] - mn);
      float p1 = __expf(sacc[1][r] - mn);
      psum[r] = p0 + p1;
      int prow = ((lane >> 4) << 2) + r;
      Pw[prow*32 + (lane & 15)]      = f2bf(p0);
      Pw[prow*32 + 16 + (lane & 15)] = f2bf(p1);
    }
#pragma unroll
    for (int x = 1; x < 16; x <<= 1)
#pragma unroll
      for (int r = 0; r < 4; ++r) psum[r] += __shfl_xor(psum[r], x);
#pragma unroll
    for (int r = 0; r < 4; ++r) lrun[r] = lrun[r]*alpha[r] + psum[r];
#pragma unroll
    for (int vt = 0; vt < 8; ++vt)
#pragma unroll
      for (int r = 0; r < 4; ++r) oacc[vt][r] *= alpha[r];
    bf16x8 pa = *(const bf16x8*)(Pw + (lane & 15)*32 + lk);
#pragma unroll
    for (int vt = 0; vt < 8; ++vt) {
      bf16x8 vf = *(const bf16x8*)(vbase + (long)(vt*16 + (lane & 15))*TT + s0 + lk);
      oacc[vt] = __builtin_amdgcn_mfma_f32_16x16x32_bf16(pa, vf, oacc[vt], 0, 0, 0);
    }
  }
  float inv[4];
#pragma unroll
  for (int r = 0; r < 4; ++r) inv[r] = 1.f / lrun[r];
#pragma unroll
  for (int vt = 0; vt < 8; ++vt)
#pragma unroll
    for (int r = 0; r < 4; ++r) {
      long row = browq + ((lane >> 4) << 2) + r;
      int col = h*128 + vt*16 + (lane & 15);
      O[row * 2048 + col] = f2bf(oacc[vt][r] * inv[r]);
    }
}

// ---------------- host ----------------
static inline long minl(long a, long b) { return a < b ? a : b; }
static inline int cgrid(long n) { return (int)minl((n/4 + 255)/256, 4096L); }

extern "C" void kernel_launch(void* const* d_in, const int* in_sizes, int n_in,
                              void* d_out, int out_size, void* d_ws, size_t ws_size,
                              hipStream_t stream) {
  const float* x    = (const float*)d_in[0];
  const float* fcos = (const float*)d_in[1];
  const float* fsin = (const float*)d_in[2];
  // d_in[3] = mask (causal tril) -- applied analytically
  const float* qdw  = (const float*)d_in[4];
  const float* qnw  = (const float*)d_in[5];
  const float* qunw = (const float*)d_in[6];
  const float* qurw = (const float*)d_in[7];
  const float* kvdw = (const float*)d_in[8];
  const float* kvnw = (const float*)d_in[9];
  const float* kvuw = (const float*)d_in[10];
  const float* wow  = (const float*)d_in[11];
  float* out = (float*)d_out;

  char* p = (char*)d_ws;
  auto alloc = [&](size_t bytes) { char* r = p; p += (bytes + 255) & ~(size_t)255; return r; };

  // arena: 227,016,704 B total (fits 256 MiB ws with 41 MB margin)
  u16* xb    = (u16*)alloc((size_t)ROWS*2048*2);   // 33.5 MB; reused as O after kv_down
  u16* w_qd  = (u16*)alloc((size_t)1536*2048*2);
  u16* w_qun = (u16*)alloc((size_t)2048*1536*2);
  u16* w_qur = (u16*)alloc((size_t)1024*1536*2);
  u16* w_kvd = (u16*)alloc((size_t)640*2048*2);    // padded N: 576 -> 640
  u16* w_kvu = (u16*)alloc((size_t)4096*512*2);
  u16* w_wo  = (u16*)alloc((size_t)2048*2048*2);
  u16* c_q   = (u16*)alloc((size_t)ROWS*1536*2);   // dead after q_up gemms } together exactly
  u16* c_kv  = (u16*)alloc((size_t)ROWS*512*2);    // dead after kv_up gemm } 33.5MB -> Vt
  u16* q_nope= (u16*)alloc((size_t)ROWS*2048*2);
  u16* q_rope= (u16*)alloc((size_t)ROWS*1024*2);
  u16* kv_bf = (u16*)alloc((size_t)ROWS*640*2);    // kv_down out (bf16)
  u16* kvb   = (u16*)alloc((size_t)ROWS*4096*2);
  u16* krope = (u16*)alloc((size_t)ROWS*64*2);

  u16* Vt = c_q;   // [B*H,128,T] = 33,554,432 B, aliases c_q(25.2MB)+c_kv(8.4MB)
  u16* Ob = xb;    // xb dead after kv_down GEMM

  const float QSC = 0.07216878364870322f;  // 1/sqrt(192), baked into q path

  // casts
  cast_bf16<<<cgrid((long)ROWS*2048), 256, 0, stream>>>(x, xb, (long)ROWS*2048, 1.f);
  cast_bf16<<<cgrid(1536L*2048), 256, 0, stream>>>(qdw, w_qd, 1536L*2048, 1.f);
  cast_bf16<<<cgrid(2048L*1536), 256, 0, stream>>>(qunw, w_qun, 2048L*1536, QSC);
  cast_bf16<<<cgrid(1024L*1536), 256, 0, stream>>>(qurw, w_qur, 1024L*1536, 1.f);
  cast_pad<<<cgrid(640L*2048), 256, 0, stream>>>(kvdw, w_kvd, 576L*2048, 640L*2048);
  cast_bf16<<<cgrid(4096L*512), 256, 0, stream>>>(kvuw, w_kvu, 4096L*512, 1.f);
  cast_bf16<<<cgrid(2048L*2048), 256, 0, stream>>>(wow, w_wo, 2048L*2048, 1.f);

  // q path
  gemm_bt<1><<<dim3(1536/128, ROWS/128), 256, 0, stream>>>(xb, w_qd, c_q, ROWS, 1536, 2048);
  rmsnorm_bf<<<ROWS, 256, 0, stream>>>(c_q, 1536, qnw, c_q, 1536, 1536, 1.f/1536.f);
  gemm_bt<1><<<dim3(2048/128, ROWS/128), 256, 0, stream>>>(c_q, w_qun, q_nope, ROWS, 2048, 1536);
  gemm_bt<1><<<dim3(1024/128, ROWS/128), 256, 0, stream>>>(c_q, w_qur, q_rope, ROWS, 1024, 1536);

  // kv path
  gemm_bt<1><<<dim3(640/128, ROWS/128), 256, 0, stream>>>(xb, w_kvd, kv_bf, ROWS, 640, 2048);
  rmsnorm_bf<<<ROWS, 256, 0, stream>>>(kv_bf, 640, kvnw, c_kv, 512, 512, 1.f/512.f);
  gemm_bt<1><<<dim3(4096/128, ROWS/128), 256, 0, stream>>>(c_kv, w_kvu, kvb, ROWS, 4096, 512);

  // rope (q in-place + k_rope), then V transpose (Vt overwrites dead c_q/c_kv)
  rope_qk<<<ROWS, 256, 0, stream>>>(q_rope, kv_bf, krope, fcos, fsin);
  transpose_v<<<dim3(TT/64, BB*HH), 256, 0, stream>>>(kvb, Vt);

  // attention (writes Ob = xb region)
  flash_attn<<<dim3(TT/64, BB*HH), 256, 0, stream>>>(q_nope, q_rope, kvb, krope, Vt, Ob);

  // output projection (fp32 out)
  gemm_bt<0><<<dim3(2048/128, ROWS/128), 256, 0, stream>>>(Ob, w_wo, out, ROWS, 2048, 2048);
}

// Round 3
// 716.813 us; speedup vs baseline: 2.2435x; 2.2435x over previous
//
#include <hip/hip_runtime.h>

#define BB 4
#define TT 2048
#define HH 16
#define ROWS (BB*TT)

typedef unsigned short u16;
typedef __bf16 bf16x8 __attribute__((ext_vector_type(8)));
typedef float f32x4 __attribute__((ext_vector_type(4)));
typedef u16 u16x8 __attribute__((ext_vector_type(8)));
typedef u16 u16x4 __attribute__((ext_vector_type(4)));

__device__ __forceinline__ u16 f2bf(float f) {
  unsigned u = __float_as_uint(f);
  u += 0x7fffu + ((u >> 16) & 1u);
  return (u16)(u >> 16);
}
__device__ __forceinline__ float bf2f(u16 h) {
  return __uint_as_float(((unsigned)h) << 16);
}

__device__ __forceinline__ void gload_lds16(const u16* g, u16* l) {
  __builtin_amdgcn_global_load_lds((const __attribute__((address_space(1))) void*)g,
                                   (__attribute__((address_space(3))) void*)l, 16, 0, 0);
}

// ---------------- cast fp32 -> bf16 (optionally scaled) ----------------
__global__ __launch_bounds__(256) void cast_bf16(const float* __restrict__ in,
                                                 u16* __restrict__ out,
                                                 long n, float scale) {
  long i = ((long)blockIdx.x * 256 + threadIdx.x) * 4;
  long stride = (long)gridDim.x * 1024;
  for (; i < n; i += stride) {
    float4 v = *(const float4*)(in + i);
    u16x4 o = { f2bf(v.x*scale), f2bf(v.y*scale), f2bf(v.z*scale), f2bf(v.w*scale) };
    *(u16x4*)(out + i) = o;
  }
}

__global__ __launch_bounds__(256) void cast_pad(const float* __restrict__ in,
                                                u16* __restrict__ out,
                                                long n_in, long n_total) {
  long i = ((long)blockIdx.x * 256 + threadIdx.x) * 4;
  long stride = (long)gridDim.x * 1024;
  for (; i < n_total; i += stride) {
    u16x4 o;
    if (i + 3 < n_in) {
      float4 v = *(const float4*)(in + i);
      o = (u16x4){ f2bf(v.x), f2bf(v.y), f2bf(v.z), f2bf(v.w) };
    } else {
#pragma unroll
      for (int e = 0; e < 4; ++e) o[e] = (i + e < n_in) ? f2bf(in[i+e]) : (u16)0;
    }
    *(u16x4*)(out + i) = o;
  }
}

// ---------------- GEMM: C[M,N] = A[M,K] (bf16) * B[N,K]^T (bf16) ----------------
template<int OUT_BF16>
__global__ __launch_bounds__(256) void gemm_bt(const u16* __restrict__ A,
                                               const u16* __restrict__ Bm,
                                               void* __restrict__ Cv,
                                               int M, int N, int K) {
  __shared__ __align__(16) u16 As[128*64];
  __shared__ __align__(16) u16 Bs[128*64];
  const int tid = threadIdx.x;
  const int lane = tid & 63;
  const int wid = tid >> 6;
  const int m0 = blockIdx.y << 7;
  const int n0 = blockIdx.x << 7;
  const int wm = (wid >> 1) << 6;
  const int wn = (wid & 1) << 6;
  const int lrow = lane & 15;
  const int lk = (lane >> 4) << 3;

  f32x4 acc[4][4] = {};

  for (int k0 = 0; k0 < K; k0 += 64) {
#pragma unroll
    for (int c = 0; c < 4; ++c) {
      int idx = c*256 + tid;
      int r = idx >> 3;
      int col = (idx & 7) << 3;
      const u16* ga = A  + (long)(m0 + r) * K + k0 + col;
      const u16* gb = Bm + (long)(n0 + r) * K + k0 + col;
      u16* la = As + (c*256 + (wid << 6)) * 8;
      u16* lb = Bs + (c*256 + (wid << 6)) * 8;
      gload_lds16(ga, la);
      gload_lds16(gb, lb);
    }
    __syncthreads();
    bf16x8 af[4][2], bfr[4][2];
#pragma unroll
    for (int m = 0; m < 4; ++m) {
      af[m][0] = *(const bf16x8*)(As + (wm + m*16 + lrow)*64 + lk);
      af[m][1] = *(const bf16x8*)(As + (wm + m*16 + lrow)*64 + 32 + lk);
    }
#pragma unroll
    for (int n = 0; n < 4; ++n) {
      bfr[n][0] = *(const bf16x8*)(Bs + (wn + n*16 + lrow)*64 + lk);
      bfr[n][1] = *(const bf16x8*)(Bs + (wn + n*16 + lrow)*64 + 32 + lk);
    }
#pragma unroll
    for (int ks = 0; ks < 2; ++ks)
#pragma unroll
      for (int m = 0; m < 4; ++m)
#pragma unroll
        for (int n = 0; n < 4; ++n)
          acc[m][n] = __builtin_amdgcn_mfma_f32_16x16x32_bf16(af[m][ks], bfr[n][ks], acc[m][n], 0, 0, 0);
    __syncthreads();
  }

  const int orow = (lane >> 4) << 2;
  const int ocol = lane & 15;
#pragma unroll
  for (int m = 0; m < 4; ++m)
#pragma unroll
    for (int n = 0; n < 4; ++n) {
      long rbase = (long)(m0 + wm + m*16 + orow);
      int col = n0 + wn + n*16 + ocol;
#pragma unroll
      for (int r = 0; r < 4; ++r) {
        if (OUT_BF16) ((u16*)Cv)[(rbase + r) * (long)N + col] = f2bf(acc[m][n][r]);
        else          ((float*)Cv)[(rbase + r) * (long)N + col] = acc[m][n][r];
      }
    }
}

// ---------------- RMSNorm (bf16 in -> bf16 out, fp32 accumulate) ----------------
__global__ __launch_bounds__(256) void rmsnorm_bf(const u16* __restrict__ in, int istride,
                                                  const float* __restrict__ w,
                                                  u16* __restrict__ out, int ostride,
                                                  int N, float invn) {
  const long row = blockIdx.x;
  const u16* x = in + row * istride;
  u16* y = out + row * ostride;
  float ss = 0.f;
  for (int i = threadIdx.x * 8; i < N; i += 2048) {
    u16x8 v = *(const u16x8*)(x + i);
#pragma unroll
    for (int e = 0; e < 8; ++e) { float f = bf2f(v[e]); ss += f*f; }
  }
#pragma unroll
  for (int off = 32; off > 0; off >>= 1) ss += __shfl_down(ss, off);
  __shared__ float red[4];
  if ((threadIdx.x & 63) == 0) red[threadIdx.x >> 6] = ss;
  __syncthreads();
  float rms = rsqrtf((red[0]+red[1]+red[2]+red[3]) * invn + 1e-6f);
  for (int i = threadIdx.x * 8; i < N; i += 2048) {
    u16x8 v = *(const u16x8*)(x + i);
    u16x8 o;
#pragma unroll
    for (int e = 0; e < 8; ++e) o[e] = f2bf(bf2f(v[e]) * rms * w[i+e]);
    *(u16x8*)(y + i) = o;
  }
}

// ---------------- RoPE ----------------
__global__ __launch_bounds__(256) void rope_qk(u16* __restrict__ qr,
                                               const u16* __restrict__ kvb0,
                                               u16* __restrict__ Kr,
                                               const float* __restrict__ cosb,
                                               const float* __restrict__ sinb) {
  const int row = blockIdx.x;
  const int t = row & (TT-1);
  const float sc = 0.07216878364870322f;   // 1/sqrt(192)
  for (int p = threadIdx.x; p < 512; p += 256) {
    int h = p >> 5, i = p & 31;
    long base = (long)row*1024 + h*64 + 2*i;
    float x0 = bf2f(qr[base]), x1 = bf2f(qr[base+1]);
    float c = cosb[t*32 + i], s = sinb[t*32 + i];
    qr[base]   = f2bf((x0*c - x1*s)*sc);
    qr[base+1] = f2bf((x0*s + x1*c)*sc);
  }
  if (threadIdx.x < 32) {
    int i = threadIdx.x;
    float x0 = bf2f(kvb0[(long)row*640 + 512 + 2*i]);
    float x1 = bf2f(kvb0[(long)row*640 + 512 + 2*i + 1]);
    float c = cosb[t*32 + i], s = sinb[t*32 + i];
    Kr[row*64 + 2*i]   = f2bf(x0*c - x1*s);
    Kr[row*64 + 2*i+1] = f2bf(x0*s + x1*c);
  }
}

// ---------------- V transpose: kv[...,h*256+128+d] -> Vt[b,h,d,t] ----------------
__global__ __launch_bounds__(256) void transpose_v(const u16* __restrict__ kvb,
                                                   u16* __restrict__ Vt) {
  __shared__ u16 tile[64][136];
  const int bh = blockIdx.y;
  const int t0 = blockIdx.x << 6;
  const int tid = threadIdx.x;
  const long rowbase = (long)(bh >> 4) * TT + t0;
#pragma unroll
  for (int it = 0; it < 4; ++it) {
    int r = it*16 + (tid >> 4);
    int c = (tid & 15) << 3;
    u16x8 v = *(const u16x8*)(kvb + (rowbase + r) * 4096 + (bh & 15) * 256 + 128 + c);
#pragma unroll
    for (int e = 0; e < 8; ++e) tile[r][c+e] = v[e];
  }
  __syncthreads();
#pragma unroll
  for (int it = 0; it < 4; ++it) {
    int d = it*32 + (tid >> 3);
    int tc = (tid & 7) << 3;
    u16x8 o;
#pragma unroll
    for (int e = 0; e < 8; ++e) o[e] = tile[tc+e][d];
    *(u16x8*)(Vt + ((long)bh * 128 + d) * TT + t0 + tc) = o;
  }
}

// ---------------- Flash attention v2 ----------------
// Block: 4 waves x 32 q-rows = 128 q-rows of one (b,h). KV tile 64 staged in LDS
// (XOR-swizzled rows), shared by all waves. Heavy-first + XCD-grouped remap.
// LDS layout (bytes): Kn [64][256B] @0; Kr [64][128B] @16384; Vd [128][128B] @24576;
// P per-wave [32][128B] @40960 + wid*4096. All rows XOR-swizzled: byte ^= (row&7)<<4.
__global__ __launch_bounds__(256, 2) void flash_attn2(const u16* __restrict__ qn,
                                                      const u16* __restrict__ qr,
                                                      const u16* __restrict__ kvb,
                                                      const u16* __restrict__ kr,
                                                      const u16* __restrict__ Vt,
                                                      u16* __restrict__ O) {
  __shared__ __align__(16) u16 lds[28672];   // 57344 B
  const int myid = blockIdx.y * 16 + blockIdx.x;            // dispatch-linear
  const int bh = (myid & 7) * 8 + ((myid >> 3) & 7);        // XCD-grouped
  const int qt = 15 - (myid >> 6);                          // heavy tiles first
  const int b = bh >> 4, h = bh & 15;
  const int wid = threadIdx.x >> 6, lane = threadIdx.x & 63;
  const int q0 = qt*128 + wid*32;                           // wave's q base (abs in seq)
  const long browq = (long)b * TT + q0;
  const long browk = (long)b * TT;
  const int l16 = lane >> 4;          // 0..3
  const int l8  = lane >> 3;          // 0..7
  const int lx16   = (lane & 15) * 16;
  const int lx8_16 = (lane & 7) * 16;
  const int co = (lane >> 4) * 16;    // fragment k-offset in bytes

  // Q fragments (A-operand), held in registers for the whole kernel
  bf16x8 qf[2][6];
#pragma unroll
  for (int f = 0; f < 2; ++f) {
    long row = browq + f*16 + (lane & 15);
#pragma unroll
    for (int ks = 0; ks < 4; ++ks)
      qf[f][ks] = *(const bf16x8*)(qn + row * 2048 + h*128 + ks*32 + (lane >> 4) * 8);
#pragma unroll
    for (int ks = 0; ks < 2; ++ks)
      qf[f][4+ks] = *(const bf16x8*)(qr + row * 1024 + h*64 + ks*32 + (lane >> 4) * 8);
  }

  f32x4 oacc[2][8] = {};
  float mrun[2][4], lrun[2][4];
#pragma unroll
  for (int f = 0; f < 2; ++f)
#pragma unroll
    for (int r = 0; r < 4; ++r) { mrun[f][r] = -1e30f; lrun[f][r] = 0.f; }

  u16* pw = lds + 20480 + wid * 2048;   // this wave's P region

  const int nIter = 2*qt + 2;
  for (int it = 0; it < nIter; ++it) {
    const int s0 = it * 64;
    // ---- stage K/V tile (each wave issues 10 x 1KB global_load_lds) ----
#pragma unroll
    for (int j = 0; j < 4; ++j) {            // Kn: 16 chunks
      int c = j*4 + wid;
      int r = c*4 + l16;
      int cb = lx16 ^ ((r & 7) << 4);
      const u16* src = (const u16*)((const char*)kvb + (browk + s0 + r) * 8192 + h * 512 + cb);
      gload_lds16(src, lds + c*512);
    }
#pragma unroll
    for (int j = 0; j < 2; ++j) {            // Kr: 8 chunks
      int c = j*4 + wid;
      int r = c*8 + l8;
      int cb = lx8_16 ^ ((r & 7) << 4);
      const u16* src = (const u16*)((const char*)kr + (browk + s0 + r) * 128 + cb);
      gload_lds16(src, lds + 8192 + c*512);
    }
#pragma unroll
    for (int j = 0; j < 4; ++j) {            // Vd: 16 chunks
      int c = j*4 + wid;
      int d = c*8 + l8;
      int cb = lx8_16 ^ ((d & 7) << 4);
      const u16* src = (const u16*)((const char*)Vt + ((long)bh*128 + d) * (TT*2) + (long)s0*2 + cb);
      gload_lds16(src, lds + 12288 + c*512);
    }
    __syncthreads();   // drains vmcnt

    const bool skip0 = s0 > q0 + 15;
    const bool skip1 = s0 > q0 + 31;
    if (!skip0 || !skip1) {
      __builtin_amdgcn_s_setprio(1);
      // ---- QK^T ----
      f32x4 sacc[2][4] = {};
#pragma unroll
      for (int nt = 0; nt < 4; ++nt) {
        const int r = nt*16 + (lane & 15);
        const int swz = (r & 7) << 4;
        bf16x8 kf[6];
#pragma unroll
        for (int ks = 0; ks < 4; ++ks)
          kf[ks] = *(const bf16x8*)((const char*)lds + r*256 + ((ks*64 + co) ^ swz));
#pragma unroll
        for (int ks = 0; ks < 2; ++ks)
          kf[4+ks] = *(const bf16x8*)((const char*)lds + 16384 + r*128 + ((ks*64 + co) ^ swz));
        if (!skip0) {
#pragma unroll
          for (int ks = 0; ks < 6; ++ks)
            sacc[0][nt] = __builtin_amdgcn_mfma_f32_16x16x32_bf16(qf[0][ks], kf[ks], sacc[0][nt], 0, 0, 0);
        }
        if (!skip1) {
#pragma unroll
          for (int ks = 0; ks < 6; ++ks)
            sacc[1][nt] = __builtin_amdgcn_mfma_f32_16x16x32_bf16(qf[1][ks], kf[ks], sacc[1][nt], 0, 0, 0);
        }
      }
      // ---- online softmax per fragment ----
#pragma unroll
      for (int f = 0; f < 2; ++f) {
        const bool skipf = f ? skip1 : skip0;
        if (skipf) continue;
        const int qmin = q0 + f*16;
        const bool partf = (s0 + 63 > qmin);
        const int qb = qmin + (l16 << 2);   // this lane's absolute q-row base
        if (partf) {
#pragma unroll
          for (int nt = 0; nt < 4; ++nt) {
            int sc = s0 + nt*16 + (lane & 15);
#pragma unroll
            for (int rr = 0; rr < 4; ++rr)
              if (sc > qb + rr) sacc[f][nt][rr] = -1e30f;
          }
        }
        float tmx[4];
#pragma unroll
        for (int rr = 0; rr < 4; ++rr)
          tmx[rr] = fmaxf(fmaxf(sacc[f][0][rr], sacc[f][1][rr]),
                          fmaxf(sacc[f][2][rr], sacc[f][3][rr]));
#pragma unroll
        for (int x = 1; x < 16; x <<= 1)
#pragma unroll
          for (int rr = 0; rr < 4; ++rr) tmx[rr] = fmaxf(tmx[rr], __shfl_xor(tmx[rr], x));
        float ps[4], alpha[4];
        const int lb2 = (lane & 15) * 2;
#pragma unroll
        for (int rr = 0; rr < 4; ++rr) {
          float mn = fmaxf(mrun[f][rr], tmx[rr]);
          alpha[rr] = __expf(mrun[f][rr] - mn);
          mrun[f][rr] = mn;
          float p0 = __expf(sacc[f][0][rr] - mn);
          float p1 = __expf(sacc[f][1][rr] - mn);
          float p2 = __expf(sacc[f][2][rr] - mn);
          float p3 = __expf(sacc[f][3][rr] - mn);
          ps[rr] = (p0 + p1) + (p2 + p3);
          const int prow = f*16 + (l16 << 2) + rr;
          const int sw = (prow & 7) << 4;
          char* pb = (char*)pw + prow*128;
          *(u16*)(pb + ((     lb2) ^ sw)) = f2bf(p0);
          *(u16*)(pb + (( 32 + lb2) ^ sw)) = f2bf(p1);
          *(u16*)(pb + (( 64 + lb2) ^ sw)) = f2bf(p2);
          *(u16*)(pb + (( 96 + lb2) ^ sw)) = f2bf(p3);
        }
#pragma unroll
        for (int x = 1; x < 16; x <<= 1)
#pragma unroll
          for (int rr = 0; rr < 4; ++rr) ps[rr] += __shfl_xor(ps[rr], x);
#pragma unroll
        for (int rr = 0; rr < 4; ++rr)
          lrun[f][rr] = lrun[f][rr] * alpha[rr] + ps[rr];
#pragma unroll
        for (int vt = 0; vt < 8; ++vt)
#pragma unroll
          for (int rr = 0; rr < 4; ++rr) oacc[f][vt][rr] *= alpha[rr];
      }
      // ---- PV ----
#pragma unroll
      for (int ks = 0; ks < 2; ++ks) {
        const int cb = ks*64 + co;
        bf16x8 vf[8];
#pragma unroll
        for (int vt = 0; vt < 8; ++vt) {
          int row = vt*16 + (lane & 15);
          vf[vt] = *(const bf16x8*)((const char*)lds + 24576 + row*128 + (cb ^ ((row & 7) << 4)));
        }
#pragma unroll
        for (int f = 0; f < 2; ++f) {
          if (f ? skip1 : skip0) continue;
          int prow = f*16 + (lane & 15);
          bf16x8 pa = *(const bf16x8*)((const char*)pw + prow*128 + (cb ^ ((prow & 7) << 4)));
#pragma unroll
          for (int vt = 0; vt < 8; ++vt)
            oacc[f][vt] = __builtin_amdgcn_mfma_f32_16x16x32_bf16(pa, vf[vt], oacc[f][vt], 0, 0, 0);
        }
      }
      __builtin_amdgcn_s_setprio(0);
    }
    __syncthreads();   // all reads done before next stage
  }

  // ---- epilogue ----
#pragma unroll
  for (int f = 0; f < 2; ++f) {
    float inv[4];
#pragma unroll
    for (int rr = 0; rr < 4; ++rr) inv[rr] = 1.f / lrun[f][rr];
#pragma unroll
    for (int vt = 0; vt < 8; ++vt)
#pragma unroll
      for (int rr = 0; rr < 4; ++rr) {
        long row = browq + f*16 + (l16 << 2) + rr;
        int col = h*128 + vt*16 + (lane & 15);
        O[row * 2048 + col] = f2bf(oacc[f][vt][rr] * inv[rr]);
      }
  }
}

// ---------------- host ----------------
static inline long minl(long a, long b) { return a < b ? a : b; }
static inline int cgrid(long n) { return (int)minl((n/4 + 255)/256, 4096L); }

extern "C" void kernel_launch(void* const* d_in, const int* in_sizes, int n_in,
                              void* d_out, int out_size, void* d_ws, size_t ws_size,
                              hipStream_t stream) {
  const float* x    = (const float*)d_in[0];
  const float* fcos = (const float*)d_in[1];
  const float* fsin = (const float*)d_in[2];
  const float* qdw  = (const float*)d_in[4];
  const float* qnw  = (const float*)d_in[5];
  const float* qunw = (const float*)d_in[6];
  const float* qurw = (const float*)d_in[7];
  const float* kvdw = (const float*)d_in[8];
  const float* kvnw = (const float*)d_in[9];
  const float* kvuw = (const float*)d_in[10];
  const float* wow  = (const float*)d_in[11];
  float* out = (float*)d_out;

  char* p = (char*)d_ws;
  auto alloc = [&](size_t bytes) { char* r = p; p += (bytes + 255) & ~(size_t)255; return r; };

  u16* xb    = (u16*)alloc((size_t)ROWS*2048*2);
  u16* w_qd  = (u16*)alloc((size_t)1536*2048*2);
  u16* w_qun = (u16*)alloc((size_t)2048*1536*2);
  u16* w_qur = (u16*)alloc((size_t)1024*1536*2);
  u16* w_kvd = (u16*)alloc((size_t)640*2048*2);
  u16* w_kvu = (u16*)alloc((size_t)4096*512*2);
  u16* w_wo  = (u16*)alloc((size_t)2048*2048*2);
  u16* c_q   = (u16*)alloc((size_t)ROWS*1536*2);
  u16* c_kv  = (u16*)alloc((size_t)ROWS*512*2);
  u16* q_nope= (u16*)alloc((size_t)ROWS*2048*2);
  u16* q_rope= (u16*)alloc((size_t)ROWS*1024*2);
  u16* kv_bf = (u16*)alloc((size_t)ROWS*640*2);
  u16* kvb   = (u16*)alloc((size_t)ROWS*4096*2);
  u16* krope = (u16*)alloc((size_t)ROWS*64*2);

  u16* Vt = c_q;   // aliases dead c_q/c_kv (33.5 MB)
  u16* Ob = xb;    // xb dead after kv_down GEMM

  const float QSC = 0.07216878364870322f;

  cast_bf16<<<cgrid((long)ROWS*2048), 256, 0, stream>>>(x, xb, (long)ROWS*2048, 1.f);
  cast_bf16<<<cgrid(1536L*2048), 256, 0, stream>>>(qdw, w_qd, 1536L*2048, 1.f);
  cast_bf16<<<cgrid(2048L*1536), 256, 0, stream>>>(qunw, w_qun, 2048L*1536, QSC);
  cast_bf16<<<cgrid(1024L*1536), 256, 0, stream>>>(qurw, w_qur, 1024L*1536, 1.f);
  cast_pad<<<cgrid(640L*2048), 256, 0, stream>>>(kvdw, w_kvd, 576L*2048, 640L*2048);
  cast_bf16<<<cgrid(4096L*512), 256, 0, stream>>>(kvuw, w_kvu, 4096L*512, 1.f);
  cast_bf16<<<cgrid(2048L*2048), 256, 0, stream>>>(wow, w_wo, 2048L*2048, 1.f);

  gemm_bt<1><<<dim3(1536/128, ROWS/128), 256, 0, stream>>>(xb, w_qd, c_q, ROWS, 1536, 2048);
  rmsnorm_bf<<<ROWS, 256, 0, stream>>>(c_q, 1536, qnw, c_q, 1536, 1536, 1.f/1536.f);
  gemm_bt<1><<<dim3(2048/128, ROWS/128), 256, 0, stream>>>(c_q, w_qun, q_nope, ROWS, 2048, 1536);
  gemm_bt<1><<<dim3(1024/128, ROWS/128), 256, 0, stream>>>(c_q, w_qur, q_rope, ROWS, 1024, 1536);

  gemm_bt<1><<<dim3(640/128, ROWS/128), 256, 0, stream>>>(xb, w_kvd, kv_bf, ROWS, 640, 2048);
  rmsnorm_bf<<<ROWS, 256, 0, stream>>>(kv_bf, 640, kvnw, c_kv, 512, 512, 1.f/512.f);
  gemm_bt<1><<<dim3(4096/128, ROWS/128), 256, 0, stream>>>(c_kv, w_kvu, kvb, ROWS, 4096, 512);

  rope_qk<<<ROWS, 256, 0, stream>>>(q_rope, kv_bf, krope, fcos, fsin);
  transpose_v<<<dim3(TT/64, BB*HH), 256, 0, stream>>>(kvb, Vt);

  flash_attn2<<<dim3(16, 64), 256, 0, stream>>>(q_nope, q_rope, kvb, krope, Vt, Ob);

  gemm_bt<0><<<dim3(2048/128, ROWS/128), 256, 0, stream>>>(Ob, w_wo, out, ROWS, 2048, 2048);
}

// Round 4
// 638.513 us; speedup vs baseline: 2.5186x; 1.1226x over previous
//
#include <hip/hip_runtime.h>

#define BB 4
#define TT 2048
#define HH 16
#define ROWS (BB*TT)

typedef unsigned short u16;
typedef __bf16 bf16x8 __attribute__((ext_vector_type(8)));
typedef float f32x4 __attribute__((ext_vector_type(4)));
typedef u16 u16x8 __attribute__((ext_vector_type(8)));
typedef u16 u16x4 __attribute__((ext_vector_type(4)));

__device__ __forceinline__ u16 f2bf(float f) {
  unsigned u = __float_as_uint(f);
  u += 0x7fffu + ((u >> 16) & 1u);
  return (u16)(u >> 16);
}
__device__ __forceinline__ float bf2f(u16 h) {
  return __uint_as_float(((unsigned)h) << 16);
}

__device__ __forceinline__ void gload_lds16(const u16* g, u16* l) {
  __builtin_amdgcn_global_load_lds((const __attribute__((address_space(1))) void*)g,
                                   (__attribute__((address_space(3))) void*)l, 16, 0, 0);
}

// ---------------- cast fp32 -> bf16 (optionally scaled) ----------------
__global__ __launch_bounds__(256) void cast_bf16(const float* __restrict__ in,
                                                 u16* __restrict__ out,
                                                 long n, float scale) {
  long i = ((long)blockIdx.x * 256 + threadIdx.x) * 4;
  long stride = (long)gridDim.x * 1024;
  for (; i < n; i += stride) {
    float4 v = *(const float4*)(in + i);
    u16x4 o = { f2bf(v.x*scale), f2bf(v.y*scale), f2bf(v.z*scale), f2bf(v.w*scale) };
    *(u16x4*)(out + i) = o;
  }
}

__global__ __launch_bounds__(256) void cast_pad(const float* __restrict__ in,
                                                u16* __restrict__ out,
                                                long n_in, long n_total) {
  long i = ((long)blockIdx.x * 256 + threadIdx.x) * 4;
  long stride = (long)gridDim.x * 1024;
  for (; i < n_total; i += stride) {
    u16x4 o;
    if (i + 3 < n_in) {
      float4 v = *(const float4*)(in + i);
      o = (u16x4){ f2bf(v.x), f2bf(v.y), f2bf(v.z), f2bf(v.w) };
    } else {
#pragma unroll
      for (int e = 0; e < 4; ++e) o[e] = (i + e < n_in) ? f2bf(in[i+e]) : (u16)0;
    }
    *(u16x4*)(out + i) = o;
  }
}

// ---------------- GEMM 256x256, 8 waves, BK=64, 2-deep dbuf + counted vmcnt ----------------
// C[M,N] = A[M,K](lda) * B[N,K]^T. LDS: buf d at d*65536: A[256][64] swizzled, B at +32768.
// Swizzle: lds_byte(row,colb) = row*128 + (colb ^ ((row&7)<<4)); staged via pre-swizzled
// global source + linear LDS dest (both-sides rule #21). vmcnt(8) per iter (2-deep prefetch,
// never drained to 0 in steady state = T4).
template<int OUT_BF16>
__global__ __launch_bounds__(512, 2) void gemm256(const u16* __restrict__ A,
                                                  const u16* __restrict__ Bm,
                                                  void* __restrict__ Cv,
                                                  int M, int N, int K, int lda) {
  __shared__ __align__(16) u16 lds[65536];   // 131072 B
  const int tid = threadIdx.x;
  const int lane = tid & 63, wid = tid >> 6;
  const int wm = (wid >> 2) * 128;
  const int wn = (wid & 3) * 64;

  // XCD-aware bijective swizzle (all grids used are divisible by 8)
  const int nx = gridDim.x;
  int id = blockIdx.y * nx + blockIdx.x;
  const int cpx = (nx * gridDim.y) >> 3;
  id = (id & 7) * cpx + (id >> 3);
  const int m0 = (id / nx) * 256;
  const int n0 = (id % nx) * 256;

  const int NT = K >> 6;

  f32x4 acc[8][4] = {};

  auto stage = [&](int kt, int d) {
#pragma unroll
    for (int j = 0; j < 4; ++j) {
      int c = j*512 + tid;                 // 16B chunk index 0..2047
      int row = c >> 3;
      int colb = (c & 7) << 4;
      int srcb = colb ^ ((row & 7) << 4);
      const u16* ga = (const u16*)((const char*)A + ((long)(m0 + row) * lda + kt*64) * 2 + srcb);
      gload_lds16(ga, (u16*)((char*)lds + d*65536 + c*16));
      const u16* gb = (const u16*)((const char*)Bm + ((long)(n0 + row) * K + kt*64) * 2 + srcb);
      gload_lds16(gb, (u16*)((char*)lds + d*65536 + 32768 + c*16));
    }
  };

  stage(0, 0);
  stage(1, 1);                     // NT >= 2 always (min K = 512)

  const int lr = lane & 15;
  const int kb = (lane >> 4) << 4;

  for (int kt = 0; kt < NT; ++kt) {
    const int cur = kt & 1;
    if (kt + 1 < NT) asm volatile("s_waitcnt vmcnt(8)" ::: "memory");
    else             asm volatile("s_waitcnt vmcnt(0)" ::: "memory");
    __builtin_amdgcn_s_barrier();
    __builtin_amdgcn_sched_barrier(0);

    const char* Ab = (const char*)lds + cur*65536;
    const char* Bb = Ab + 32768;
#pragma unroll
    for (int qd = 0; qd < 4; ++qd) {       // C-quadrants: 16 MFMA each
      const int mb = (qd >> 1) * 4;
      const int nb = (qd & 1) * 2;
      bf16x8 af[4][2], bf[2][2];
#pragma unroll
      for (int i = 0; i < 4; ++i) {
        int r = wm + (mb + i)*16 + lr;
#pragma unroll
        for (int ks = 0; ks < 2; ++ks)
          af[i][ks] = *(const bf16x8*)(Ab + r*128 + ((ks*64 + kb) ^ ((r & 7) << 4)));
      }
#pragma unroll
      for (int i = 0; i < 2; ++i) {
        int r = wn + (nb + i)*16 + lr;
#pragma unroll
        for (int ks = 0; ks < 2; ++ks)
          bf[i][ks] = *(const bf16x8*)(Bb + r*128 + ((ks*64 + kb) ^ ((r & 7) << 4)));
      }
      __builtin_amdgcn_s_setprio(1);
#pragma unroll
      for (int ks = 0; ks < 2; ++ks)
#pragma unroll
        for (int i = 0; i < 4; ++i)
#pragma unroll
          for (int j = 0; j < 2; ++j)
            acc[mb+i][nb+j] = __builtin_amdgcn_mfma_f32_16x16x32_bf16(af[i][ks], bf[j][ks], acc[mb+i][nb+j], 0, 0, 0);
      __builtin_amdgcn_s_setprio(0);
    }
    __builtin_amdgcn_sched_barrier(0);
    __builtin_amdgcn_s_barrier();          // all waves done reading buf[cur]
    if (kt + 2 < NT) stage(kt + 2, cur);
  }

  const int orow = (lane >> 4) << 2;
  const int ocol = lane & 15;
#pragma unroll
  for (int mf = 0; mf < 8; ++mf)
#pragma unroll
    for (int nf = 0; nf < 4; ++nf) {
      long rbase = (long)(m0 + wm + mf*16 + orow);
      int col = n0 + wn + nf*16 + ocol;
#pragma unroll
      for (int rr = 0; rr < 4; ++rr) {
        if (OUT_BF16) ((u16*)Cv)[(rbase + rr) * (long)N + col] = f2bf(acc[mf][nf][rr]);
        else          ((float*)Cv)[(rbase + rr) * (long)N + col] = acc[mf][nf][rr];
      }
    }
}

// ---------------- RMSNorm (bf16 in -> bf16 out, fp32 accumulate, strided/in-place) ----------------
__global__ __launch_bounds__(256) void rmsnorm_bf(const u16* __restrict__ in, int istride,
                                                  const float* __restrict__ w,
                                                  u16* __restrict__ out, int ostride,
                                                  int N, float invn) {
  const long row = blockIdx.x;
  const u16* x = in + row * istride;
  u16* y = out + row * ostride;
  float ss = 0.f;
  for (int i = threadIdx.x * 8; i < N; i += 2048) {
    u16x8 v = *(const u16x8*)(x + i);
#pragma unroll
    for (int e = 0; e < 8; ++e) { float f = bf2f(v[e]); ss += f*f; }
  }
#pragma unroll
  for (int off = 32; off > 0; off >>= 1) ss += __shfl_down(ss, off);
  __shared__ float red[4];
  if ((threadIdx.x & 63) == 0) red[threadIdx.x >> 6] = ss;
  __syncthreads();
  float rms = rsqrtf((red[0]+red[1]+red[2]+red[3]) * invn + 1e-6f);
  for (int i = threadIdx.x * 8; i < N; i += 2048) {
    u16x8 v = *(const u16x8*)(x + i);
    u16x8 o;
#pragma unroll
    for (int e = 0; e < 8; ++e) o[e] = f2bf(bf2f(v[e]) * rms * w[i+e]);
    *(u16x8*)(y + i) = o;
  }
}

// ---------------- RoPE: q_cat rope cols in-place (+scale), k_rope -> Kr ----------------
__global__ __launch_bounds__(256) void rope_qk(u16* __restrict__ qcat,      // [ROWS,3072], rope @+2048
                                               const u16* __restrict__ dk,  // [ROWS,2304], k_rope @+2048
                                               u16* __restrict__ Kr,        // [ROWS,64]
                                               const float* __restrict__ cosb,
                                               const float* __restrict__ sinb) {
  const int row = blockIdx.x;
  const int t = row & (TT-1);
  const float sc = 0.07216878364870322f;   // 1/sqrt(192)
  for (int p = threadIdx.x; p < 512; p += 256) {
    int h = p >> 5, i = p & 31;
    long base = (long)row*3072 + 2048 + h*64 + 2*i;
    float x0 = bf2f(qcat[base]), x1 = bf2f(qcat[base+1]);
    float c = cosb[t*32 + i], s = sinb[t*32 + i];
    qcat[base]   = f2bf((x0*c - x1*s)*sc);
    qcat[base+1] = f2bf((x0*s + x1*c)*sc);
  }
  if (threadIdx.x < 32) {
    int i = threadIdx.x;
    float x0 = bf2f(dk[(long)row*2304 + 2048 + 2*i]);
    float x1 = bf2f(dk[(long)row*2304 + 2048 + 2*i + 1]);
    float c = cosb[t*32 + i], s = sinb[t*32 + i];
    Kr[row*64 + 2*i]   = f2bf(x0*c - x1*s);
    Kr[row*64 + 2*i+1] = f2bf(x0*s + x1*c);
  }
}

// ---------------- V transpose: kv[...,h*256+128+d] -> Vt[b,h,d,t] ----------------
__global__ __launch_bounds__(256) void transpose_v(const u16* __restrict__ kvb,
                                                   u16* __restrict__ Vt) {
  __shared__ u16 tile[64][136];
  const int bh = blockIdx.y;
  const int t0 = blockIdx.x << 6;
  const int tid = threadIdx.x;
  const long rowbase = (long)(bh >> 4) * TT + t0;
#pragma unroll
  for (int it = 0; it < 4; ++it) {
    int r = it*16 + (tid >> 4);
    int c = (tid & 15) << 3;
    u16x8 v = *(const u16x8*)(kvb + (rowbase + r) * 4096 + (bh & 15) * 256 + 128 + c);
#pragma unroll
    for (int e = 0; e < 8; ++e) tile[r][c+e] = v[e];
  }
  __syncthreads();
#pragma unroll
  for (int it = 0; it < 4; ++it) {
    int d = it*32 + (tid >> 3);
    int tc = (tid & 7) << 3;
    u16x8 o;
#pragma unroll
    for (int e = 0; e < 8; ++e) o[e] = tile[tc+e][d];
    *(u16x8*)(Vt + ((long)bh * 128 + d) * TT + t0 + tc) = o;
  }
}

// ---------------- Flash attention: 4 waves x 32 q-rows, KV tile 64, LDS-shared ----------------
__global__ __launch_bounds__(256, 2) void flash_attn2(const u16* __restrict__ qcat, // [ROWS,3072]
                                                      const u16* __restrict__ kvb,  // [ROWS,4096]
                                                      const u16* __restrict__ kr,   // [ROWS,64]
                                                      const u16* __restrict__ Vt,   // [B*H,128,T]
                                                      u16* __restrict__ O) {        // [ROWS,2048]
  __shared__ __align__(16) u16 lds[28672];   // 57344 B
  const int myid = blockIdx.y * 16 + blockIdx.x;
  const int bh = (myid & 7) * 8 + ((myid >> 3) & 7);
  const int qt = 15 - (myid >> 6);
  const int b = bh >> 4, h = bh & 15;
  const int wid = threadIdx.x >> 6, lane = threadIdx.x & 63;
  const int q0 = qt*128 + wid*32;
  const long browq = (long)b * TT + q0;
  const long browk = (long)b * TT;
  const int l16 = lane >> 4;
  const int l8  = lane >> 3;
  const int lx16   = (lane & 15) * 16;
  const int lx8_16 = (lane & 7) * 16;
  const int co = (lane >> 4) * 16;

  bf16x8 qf[2][6];
#pragma unroll
  for (int f = 0; f < 2; ++f) {
    long row = browq + f*16 + (lane & 15);
#pragma unroll
    for (int ks = 0; ks < 4; ++ks)
      qf[f][ks] = *(const bf16x8*)(qcat + row * 3072 + h*128 + ks*32 + (lane >> 4) * 8);
#pragma unroll
    for (int ks = 0; ks < 2; ++ks)
      qf[f][4+ks] = *(const bf16x8*)(qcat + row * 3072 + 2048 + h*64 + ks*32 + (lane >> 4) * 8);
  }

  f32x4 oacc[2][8] = {};
  float mrun[2][4], lrun[2][4];
#pragma unroll
  for (int f = 0; f < 2; ++f)
#pragma unroll
    for (int r = 0; r < 4; ++r) { mrun[f][r] = -1e30f; lrun[f][r] = 0.f; }

  u16* pw = lds + 20480 + wid * 2048;

  const int nIter = 2*qt + 2;
  for (int it = 0; it < nIter; ++it) {
    const int s0 = it * 64;
#pragma unroll
    for (int j = 0; j < 4; ++j) {            // Kn
      int c = j*4 + wid;
      int r = c*4 + l16;
      int cb = lx16 ^ ((r & 7) << 4);
      const u16* src = (const u16*)((const char*)kvb + (browk + s0 + r) * 8192 + h * 512 + cb);
      gload_lds16(src, lds + c*512);
    }
#pragma unroll
    for (int j = 0; j < 2; ++j) {            // Kr
      int c = j*4 + wid;
      int r = c*8 + l8;
      int cb = lx8_16 ^ ((r & 7) << 4);
      const u16* src = (const u16*)((const char*)kr + (browk + s0 + r) * 128 + cb);
      gload_lds16(src, lds + 8192 + c*512);
    }
#pragma unroll
    for (int j = 0; j < 4; ++j) {            // Vd
      int c = j*4 + wid;
      int d = c*8 + l8;
      int cb = lx8_16 ^ ((d & 7) << 4);
      const u16* src = (const u16*)((const char*)Vt + ((long)bh*128 + d) * (TT*2) + (long)s0*2 + cb);
      gload_lds16(src, lds + 12288 + c*512);
    }
    __syncthreads();

    const bool skip0 = s0 > q0 + 15;
    const bool skip1 = s0 > q0 + 31;
    if (!skip0 || !skip1) {
      __builtin_amdgcn_s_setprio(1);
      f32x4 sacc[2][4] = {};
#pragma unroll
      for (int nt = 0; nt < 4; ++nt) {
        const int r = nt*16 + (lane & 15);
        const int swz = (r & 7) << 4;
        bf16x8 kf[6];
#pragma unroll
        for (int ks = 0; ks < 4; ++ks)
          kf[ks] = *(const bf16x8*)((const char*)lds + r*256 + ((ks*64 + co) ^ swz));
#pragma unroll
        for (int ks = 0; ks < 2; ++ks)
          kf[4+ks] = *(const bf16x8*)((const char*)lds + 16384 + r*128 + ((ks*64 + co) ^ swz));
        if (!skip0) {
#pragma unroll
          for (int ks = 0; ks < 6; ++ks)
            sacc[0][nt] = __builtin_amdgcn_mfma_f32_16x16x32_bf16(qf[0][ks], kf[ks], sacc[0][nt], 0, 0, 0);
        }
        if (!skip1) {
#pragma unroll
          for (int ks = 0; ks < 6; ++ks)
            sacc[1][nt] = __builtin_amdgcn_mfma_f32_16x16x32_bf16(qf[1][ks], kf[ks], sacc[1][nt], 0, 0, 0);
        }
      }
#pragma unroll
      for (int f = 0; f < 2; ++f) {
        const bool skipf = f ? skip1 : skip0;
        if (skipf) continue;
        const int qmin = q0 + f*16;
        const bool partf = (s0 + 63 > qmin);
        const int qb = qmin + (l16 << 2);
        if (partf) {
#pragma unroll
          for (int nt = 0; nt < 4; ++nt) {
            int sc = s0 + nt*16 + (lane & 15);
#pragma unroll
            for (int rr = 0; rr < 4; ++rr)
              if (sc > qb + rr) sacc[f][nt][rr] = -1e30f;
          }
        }
        float tmx[4];
#pragma unroll
        for (int rr = 0; rr < 4; ++rr)
          tmx[rr] = fmaxf(fmaxf(sacc[f][0][rr], sacc[f][1][rr]),
                          fmaxf(sacc[f][2][rr], sacc[f][3][rr]));
#pragma unroll
        for (int x = 1; x < 16; x <<= 1)
#pragma unroll
          for (int rr = 0; rr < 4; ++rr) tmx[rr] = fmaxf(tmx[rr], __shfl_xor(tmx[rr], x));
        float ps[4], alpha[4];
        const int lb2 = (lane & 15) * 2;
#pragma unroll
        for (int rr = 0; rr < 4; ++rr) {
          float mn = fmaxf(mrun[f][rr], tmx[rr]);
          alpha[rr] = __expf(mrun[f][rr] - mn);
          mrun[f][rr] = mn;
          float p0 = __expf(sacc[f][0][rr] - mn);
          float p1 = __expf(sacc[f][1][rr] - mn);
          float p2 = __expf(sacc[f][2][rr] - mn);
          float p3 = __expf(sacc[f][3][rr] - mn);
          ps[rr] = (p0 + p1) + (p2 + p3);
          const int prow = f*16 + (l16 << 2) + rr;
          const int sw = (prow & 7) << 4;
          char* pb = (char*)pw + prow*128;
          *(u16*)(pb + ((     lb2) ^ sw)) = f2bf(p0);
          *(u16*)(pb + (( 32 + lb2) ^ sw)) = f2bf(p1);
          *(u16*)(pb + (( 64 + lb2) ^ sw)) = f2bf(p2);
          *(u16*)(pb + (( 96 + lb2) ^ sw)) = f2bf(p3);
        }
#pragma unroll
        for (int x = 1; x < 16; x <<= 1)
#pragma unroll
          for (int rr = 0; rr < 4; ++rr) ps[rr] += __shfl_xor(ps[rr], x);
#pragma unroll
        for (int rr = 0; rr < 4; ++rr)
          lrun[f][rr] = lrun[f][rr] * alpha[rr] + ps[rr];
#pragma unroll
        for (int vt = 0; vt < 8; ++vt)
#pragma unroll
          for (int rr = 0; rr < 4; ++rr) oacc[f][vt][rr] *= alpha[rr];
      }
#pragma unroll
      for (int ks = 0; ks < 2; ++ks) {
        const int cb = ks*64 + co;
        bf16x8 vf[8];
#pragma unroll
        for (int vt = 0; vt < 8; ++vt) {
          int row = vt*16 + (lane & 15);
          vf[vt] = *(const bf16x8*)((const char*)lds + 24576 + row*128 + (cb ^ ((row & 7) << 4)));
        }
#pragma unroll
        for (int f = 0; f < 2; ++f) {
          if (f ? skip1 : skip0) continue;
          int prow = f*16 + (lane & 15);
          bf16x8 pa = *(const bf16x8*)((const char*)pw + prow*128 + (cb ^ ((prow & 7) << 4)));
#pragma unroll
          for (int vt = 0; vt < 8; ++vt)
            oacc[f][vt] = __builtin_amdgcn_mfma_f32_16x16x32_bf16(pa, vf[vt], oacc[f][vt], 0, 0, 0);
        }
      }
      __builtin_amdgcn_s_setprio(0);
    }
    __syncthreads();
  }

#pragma unroll
  for (int f = 0; f < 2; ++f) {
    float inv[4];
#pragma unroll
    for (int rr = 0; rr < 4; ++rr) inv[rr] = 1.f / lrun[f][rr];
#pragma unroll
    for (int vt = 0; vt < 8; ++vt)
#pragma unroll
      for (int rr = 0; rr < 4; ++rr) {
        long row = browq + f*16 + (l16 << 2) + rr;
        int col = h*128 + vt*16 + (lane & 15);
        O[row * 2048 + col] = f2bf(oacc[f][vt][rr] * inv[rr]);
      }
  }
}

// ---------------- host ----------------
static inline long minl(long a, long b) { return a < b ? a : b; }
static inline int cgrid(long n) { return (int)minl((n/4 + 255)/256, 4096L); }

extern "C" void kernel_launch(void* const* d_in, const int* in_sizes, int n_in,
                              void* d_out, int out_size, void* d_ws, size_t ws_size,
                              hipStream_t stream) {
  const float* x    = (const float*)d_in[0];
  const float* fcos = (const float*)d_in[1];
  const float* fsin = (const float*)d_in[2];
  const float* qdw  = (const float*)d_in[4];
  const float* qnw  = (const float*)d_in[5];
  const float* qunw = (const float*)d_in[6];
  const float* qurw = (const float*)d_in[7];
  const float* kvdw = (const float*)d_in[8];
  const float* kvnw = (const float*)d_in[9];
  const float* kvuw = (const float*)d_in[10];
  const float* wow  = (const float*)d_in[11];
  float* out = (float*)d_out;

  char* p = (char*)d_ws;
  auto alloc = [&](size_t bytes) { char* r = p; p += (bytes + 255) & ~(size_t)255; return r; };

  // arena ~221 MB
  u16* xb   = (u16*)alloc((size_t)ROWS*2048*2);   // x bf16; later Ob (flash out)
  u16* wdc  = (u16*)alloc((size_t)2304*2048*2);   // [q_down; kv_down(pad 576->768)] rows
  u16* wuc  = (u16*)alloc((size_t)3072*1536*2);   // [q_up_nope*QSC; q_up_rope] rows
  u16* wkvu = (u16*)alloc((size_t)4096*512*2);
  u16* wwo  = (u16*)alloc((size_t)2048*2048*2);
  u16* dk   = (u16*)alloc((size_t)ROWS*2304*2);   // down out: cq|ckv|krope; later Vt
  u16* qcat = (u16*)alloc((size_t)ROWS*3072*2);   // q_nope | q_rope
  u16* kvb  = (u16*)alloc((size_t)ROWS*4096*2);
  u16* kro  = (u16*)alloc((size_t)ROWS*64*2);

  u16* Vt = dk;    // dk dead after kv_up GEMM + rope_qk
  u16* Ob = xb;    // xb dead after down GEMM

  const float QSC = 0.07216878364870322f;  // 1/sqrt(192), baked into q path

  cast_bf16<<<cgrid((long)ROWS*2048), 256, 0, stream>>>(x, xb, (long)ROWS*2048, 1.f);
  cast_bf16<<<cgrid(1536L*2048), 256, 0, stream>>>(qdw, wdc, 1536L*2048, 1.f);
  cast_pad<<<cgrid(768L*2048), 256, 0, stream>>>(kvdw, wdc + 1536L*2048, 576L*2048, 768L*2048);
  cast_bf16<<<cgrid(2048L*1536), 256, 0, stream>>>(qunw, wuc, 2048L*1536, QSC);
  cast_bf16<<<cgrid(1024L*1536), 256, 0, stream>>>(qurw, wuc + 2048L*1536, 1024L*1536, 1.f);
  cast_bf16<<<cgrid(4096L*512), 256, 0, stream>>>(kvuw, wkvu, 4096L*512, 1.f);
  cast_bf16<<<cgrid(2048L*2048), 256, 0, stream>>>(wow, wwo, 2048L*2048, 1.f);

  // fused down-projection: dk = xb @ [qdw;kvdw]^T  (N=2304)
  gemm256<1><<<dim3(9, 32), 512, 0, stream>>>(xb, wdc, dk, ROWS, 2304, 2048, 2048);
  // in-place strided RMSNorms inside dk
  rmsnorm_bf<<<ROWS, 256, 0, stream>>>(dk, 2304, qnw, dk, 2304, 1536, 1.f/1536.f);
  rmsnorm_bf<<<ROWS, 256, 0, stream>>>(dk + 1536, 2304, kvnw, dk + 1536, 2304, 512, 1.f/512.f);
  // fused q up-projection: qcat = cq @ [qun*QSC; qur]^T  (N=3072, lda=2304)
  gemm256<1><<<dim3(12, 32), 512, 0, stream>>>(dk, wuc, qcat, ROWS, 3072, 1536, 2304);
  // kv up-projection (lda=2304)
  gemm256<1><<<dim3(16, 32), 512, 0, stream>>>(dk + 1536, wkvu, kvb, ROWS, 4096, 512, 2304);
  // rope (q_cat in place + krope from dk), then Vt (overwrites dk)
  rope_qk<<<ROWS, 256, 0, stream>>>(qcat, dk, kro, fcos, fsin);
  transpose_v<<<dim3(TT/64, BB*HH), 256, 0, stream>>>(kvb, Vt);
  // attention
  flash_attn2<<<dim3(16, 64), 256, 0, stream>>>(qcat, kvb, kro, Vt, Ob);
  // output projection (fp32 out)
  gemm256<0><<<dim3(8, 32), 512, 0, stream>>>(Ob, wwo, out, ROWS, 2048, 2048, 2048);
}